// Round 6
// baseline (108.910 us; speedup 1.0000x reference)
//
#include <hip/hip_runtime.h>
#include <hip/hip_fp16.h>
#include <math.h>

#define BATCH 8
#define NSLOT 256
#define DDIM  256
#define HID   128
#define NREL  8

typedef _Float16 half8 __attribute__((ext_vector_type(8)));
typedef float float4v __attribute__((ext_vector_type(4)));

union U8 {
  uint32_t u[4];
  _Float16 f[8];
  half8 v;
  float4 f4;
};

union H4 {
  _Float16 f[4];
  double d;
};

// d_ws layout: WT f16[256][256] at offset 0 (128 KB); P f16[2048][256] at 1 MB.

// ---------------------------------------------------------------------------
// Kernel 0: WT[c][k] = (f16) Wc[k][c], where Wc[k][c] = (c<128) ? W1[k][c]
// : W1[256+k][c-128].  Combined-column, k-contiguous layout so proj's MFMA
// B-fragments become single 16-B loads. 32x32 LDS transpose tiles, 64 blocks.
// ---------------------------------------------------------------------------
__global__ __launch_bounds__(256) void wt_kernel(
    const float* __restrict__ W1, _Float16* __restrict__ WT) {
  __shared__ float T[32][33];
  const int tx = threadIdx.x & 31;
  const int ty = threadIdx.x >> 5;  // 0..7
  const int c0 = blockIdx.x * 32, k0 = blockIdx.y * 32;
#pragma unroll
  for (int p = 0; p < 4; ++p) {
    const int k = k0 + ty + p * 8;
    const int c = c0 + tx;
    T[ty + p * 8][tx] = (c < HID) ? W1[(size_t)k * HID + c]
                                  : W1[(size_t)(DDIM + k) * HID + (c - HID)];
  }
  __syncthreads();
#pragma unroll
  for (int p = 0; p < 4; ++p) {
    const int cl = ty + p * 8;
    WT[(size_t)(c0 + cl) * 256 + k0 + tx] = (_Float16)T[tx][cl];
  }
}

// ---------------------------------------------------------------------------
// Kernel 1 (v5, MFMA): P[row][c] = sum_k slots[row][k] * Wc[k][c] (+b1 for c<128)
// Grid (4 col-quarters, 128 row-tiles) = 512 blocks x 128 thr (2 waves).
// Wave w: cols [bx*64 + w*32, +32) = 2 n-tiles. Preload 16 B-frags (16-B
// contiguous loads from WT, L2-hot); stage 16x256 slots tile to LDS f16
// (pad to 264: A-frag ds_read_b128 hits the 8-lanes/bank-quad floor, no
// extra conflict); inner loop = 8 x [ds_read_b128 + 2 MFMA]. One barrier.
// MFMA mappings (validated on HW by round-5 pair kernel):
//  A[m][k]: m=lane&15, k=(lane>>4)*8+u ; B[k][n]: n=lane&15, k=(lane>>4)*8+u
//  D: col=lane&15, row=(lane>>4)*4+reg
// ---------------------------------------------------------------------------
__global__ __launch_bounds__(128) void proj_kernel(
    const float* __restrict__ slots, const _Float16* __restrict__ WT,
    const float* __restrict__ b1, _Float16* __restrict__ P) {
  __shared__ _Float16 SL[16 * 264];

  const int tid  = threadIdx.x;   // 0..127
  const int w    = tid >> 6;      // wave 0..1
  const int lane = tid & 63;
  const int lo16 = lane & 15;
  const int kg   = lane >> 4;     // 0..3
  const int row0 = blockIdx.y * 16;
  const int c0   = blockIdx.x * 64 + w * 32;

  // Preload all B-fragments: 2 n-tiles x 8 k-steps, 16 B each (64 VGPRs).
  U8 bf[2][8];
#pragma unroll
  for (int t = 0; t < 2; ++t)
#pragma unroll
    for (int ks = 0; ks < 8; ++ks)
      bf[t][ks].f4 =
          *(const float4*)(WT + (size_t)(c0 + t * 16 + lo16) * 256 + ks * 32 + kg * 8);

  // Stage slots tile: 16 rows x 256 f32 -> f16 in LDS. 1024 float4, 8/thread.
  const float* S0 = slots + (size_t)row0 * DDIM;
#pragma unroll
  for (int p = 0; p < 8; ++p) {
    const int idx = tid + p * 128;
    const int r  = idx >> 6;
    const int c4 = (idx & 63) * 4;
    const float4 f = *(const float4*)(S0 + (size_t)r * DDIM + c4);
    H4 h;
    h.f[0] = (_Float16)f.x; h.f[1] = (_Float16)f.y;
    h.f[2] = (_Float16)f.z; h.f[3] = (_Float16)f.w;
    *(double*)&SL[r * 264 + c4] = h.d;
  }
  __syncthreads();

  float4v acc0 = {0.0f, 0.0f, 0.0f, 0.0f};
  float4v acc1 = {0.0f, 0.0f, 0.0f, 0.0f};
#pragma unroll
  for (int ks = 0; ks < 8; ++ks) {
    U8 a;
    a.f4 = *(const float4*)&SL[lo16 * 264 + ks * 32 + kg * 8];
    acc0 = __builtin_amdgcn_mfma_f32_16x16x32_f16(a.v, bf[0][ks].v, acc0, 0, 0, 0);
    acc1 = __builtin_amdgcn_mfma_f32_16x16x32_f16(a.v, bf[1][ks].v, acc1, 0, 0, 0);
  }

  // Epilogue: D lane holds rows kg*4+reg, col lo16 (per n-tile). Bias for c<128.
#pragma unroll
  for (int t = 0; t < 2; ++t) {
    const int cg = c0 + t * 16 + lo16;
    const float bias = (cg < HID) ? b1[cg] : 0.0f;
    const float4v& A = t ? acc1 : acc0;
#pragma unroll
    for (int reg = 0; reg < 4; ++reg) {
      const int row = row0 + kg * 4 + reg;
      P[(size_t)row * 256 + cg] = (_Float16)(A[reg] + bias);
    }
  }
}

// ---------------------------------------------------------------------------
// Kernel 2 (v3b, UNCHANGED — validated): pair grid via f16 MFMA.
// ---------------------------------------------------------------------------
__global__ __launch_bounds__(256) void pair_kernel(
    const _Float16* __restrict__ P, const float* __restrict__ W2,
    const float* __restrict__ b2, float* __restrict__ out) {
  __shared__ uint32_t PiL[16 * 68];

  const int tid  = threadIdx.x;
  const int w    = tid >> 6;
  const int lane = tid & 63;
  const int n    = lane & 15;
  const int kg   = lane >> 4;

  const int b   = blockIdx.z;
  const int i0  = blockIdx.y * 16;
  const int j0  = blockIdx.x * 64 + w * 16;
  const _Float16* Pb = P + (size_t)b * NSLOT * 256;

  {
    const int r  = tid >> 4;
    const int ch = tid & 15;
    const float4 t = *(const float4*)(Pb + (size_t)(i0 + r) * 256 + ch * 8);
    *(float4*)&PiL[r * 68 + ch * 4] = t;
  }
  __syncthreads();

  U8 w2f[4];
#pragma unroll
  for (int kq = 0; kq < 4; ++kq) {
#pragma unroll
    for (int u = 0; u < 8; ++u) {
      const int k = kq * 32 + kg * 8 + u;
      w2f[kq].f[u] = (n < 8) ? (_Float16)W2[k * NREL + n] : (_Float16)0.0f;
    }
  }
  const float b2v = (n < 8) ? b2[n] : 0.0f;

  U8 pj[4];
#pragma unroll
  for (int kq = 0; kq < 4; ++kq) {
    pj[kq].f4 = *(const float4*)(Pb + (size_t)(j0 + n) * 256 + HID + kq * 32 + kg * 8);
  }

  for (int i = 0; i < 16; ++i) {
    float4v acc = {0.0f, 0.0f, 0.0f, 0.0f};
#pragma unroll
    for (int kq = 0; kq < 4; ++kq) {
      U8 pi;
      pi.f4 = *(const float4*)&PiL[i * 68 + kq * 16 + kg * 4];
      U8 h;
      h.v = __builtin_elementwise_max(pj[kq].v + pi.v, (half8)(_Float16)0.0f);
      acc = __builtin_amdgcn_mfma_f32_16x16x32_f16(h.v, w2f[kq].v, acc, 0, 0, 0);
    }
    if (n < 8) {
      float* obase = out + (((size_t)b * NSLOT + (i0 + i)) * NSLOT + j0) * NREL + n;
#pragma unroll
      for (int reg = 0; reg < 4; ++reg) {
        const int jrow = kg * 4 + reg;
        const float x = acc[reg] + b2v;
        obase[jrow * NREL] = __builtin_amdgcn_rcpf(1.0f + __expf(-x));
      }
    }
  }
}

extern "C" void kernel_launch(void* const* d_in, const int* in_sizes, int n_in,
                              void* d_out, int out_size, void* d_ws, size_t ws_size,
                              hipStream_t stream) {
  const float* slots = (const float*)d_in[0];  // [8,256,256]
  const float* W1    = (const float*)d_in[1];  // [512,128]
  const float* b1    = (const float*)d_in[2];  // [128]
  const float* W2    = (const float*)d_in[3];  // [128,8]
  const float* b2    = (const float*)d_in[4];  // [8]
  float* out     = (float*)d_out;              // [8,256,256,8]
  _Float16* WT   = (_Float16*)d_ws;                          // 128 KB
  _Float16* P    = (_Float16*)((char*)d_ws + (1 << 20));     // 1 MB

  wt_kernel  <<<dim3(8, 8),            256, 0, stream>>>(W1, WT);
  proj_kernel<<<dim3(4, 128),          128, 0, stream>>>(slots, WT, b1, P);
  pair_kernel<<<dim3(NSLOT / 64, NSLOT / 16, BATCH), 256, 0, stream>>>(P, W2, b2, out);
}